// Round 9
// baseline (167.943 us; speedup 1.0000x reference)
//
#include <hip/hip_runtime.h>
#include <hip/hip_bf16.h>

#define D_MODEL 1024
#define NH 16
#define HD 64
#define S_LEN 2048
#define NB 2
#define M_TOT 4096
#define N3 3072

typedef __attribute__((ext_vector_type(8))) short bf16x8;
typedef __attribute__((ext_vector_type(4))) float f32x4;
typedef __attribute__((ext_vector_type(4))) unsigned short u16x4;

__device__ __forceinline__ unsigned short f2bf(float f) {
    unsigned int u = __float_as_uint(f);
    u += 0x7fffu + ((u >> 16) & 1u);
    return (unsigned short)(u >> 16);
}
__device__ __forceinline__ float bf2f(unsigned short s) {
    return __uint_as_float((unsigned int)s << 16);
}

#define GLOAD_LDS(gp, lp)                                                      \
    __builtin_amdgcn_global_load_lds(                                          \
        (const __attribute__((address_space(1))) void*)(gp),                   \
        (__attribute__((address_space(3))) void*)(lp), 16, 0, 0)

// ---------------------------------------------------------------- fused casts
__global__ __launch_bounds__(256) void cast_both(
    const float* __restrict__ x, const float* __restrict__ W,
    unsigned short* __restrict__ xb, unsigned short* __restrict__ Wb) {
    const int nx = M_TOT * D_MODEL / 4;
    const int nw = N3 * D_MODEL / 4;
    int i = blockIdx.x * 256 + threadIdx.x;
    const float* src;
    unsigned short* dst;
    int j;
    if (i < nx) { src = x; dst = xb; j = i; }
    else { j = i - nx; if (j >= nw) return; src = W; dst = Wb; }
    float4 v = reinterpret_cast<const float4*>(src)[j];
    u16x4 o;
    o.x = f2bf(v.x); o.y = f2bf(v.y); o.z = f2bf(v.z); o.w = f2bf(v.w);
    reinterpret_cast<u16x4*>(dst)[j] = o;
}

// ---------------------------------------------------------------- QKV GEMM
// m97 structure; swapped mfma(B,A); bijective XCD swizzle (768 % 8 == 0).
#define BM 128
#define BN 128
#define BK 64

__global__ __launch_bounds__(256) void qkv_gemm(
    const unsigned short* __restrict__ A, const unsigned short* __restrict__ B,
    const float* __restrict__ bias, unsigned short* __restrict__ Z) {
    __shared__ unsigned short As[BM * BK];
    __shared__ unsigned short Bs[BN * BK];

    const int t = threadIdx.x;
    const int lane = t & 63;
    const int wid = t >> 6;
    const int wr = wid >> 1, wc = wid & 1;
    // XCD-aware swizzle: 768 workgroups, 8 XCDs, 96 per XCD (bijective)
    const int lin = blockIdx.y * 24 + blockIdx.x;
    const int swz = (lin & 7) * 96 + (lin >> 3);
    const int bm = swz / 24, bn = swz % 24;
    const int lr = lane & 15;
    const int lg = lane >> 4;
    const int srow = lane >> 3;
    const int sslot = lane & 7;

    f32x4 acc[4][4] = {};

    for (int k0 = 0; k0 < 1024; k0 += BK) {
        __syncthreads();
#pragma unroll
        for (int p = 0; p < 4; ++p) {
            int rb = wid * 32 + p * 8;
            int row = rb + srow;
            int seg = sslot ^ (row & 7);
            GLOAD_LDS(&A[(size_t)(bm * BM + row) * 1024 + k0 + seg * 8],
                      &As[rb * BK]);
            GLOAD_LDS(&B[(size_t)(bn * BN + row) * 1024 + k0 + seg * 8],
                      &Bs[rb * BK]);
        }
        __syncthreads();
#pragma unroll
        for (int ks = 0; ks < 2; ++ks) {
            bf16x8 af[4], bfr[4];
#pragma unroll
            for (int m = 0; m < 4; ++m) {
                int row = wr * 64 + m * 16 + lr;
                int slot = (ks * 4 + lg) ^ (row & 7);
                af[m] = *reinterpret_cast<const bf16x8*>(&As[row * BK + slot * 8]);
            }
#pragma unroll
            for (int n = 0; n < 4; ++n) {
                int row = wc * 64 + n * 16 + lr;
                int slot = (ks * 4 + lg) ^ (row & 7);
                bfr[n] = *reinterpret_cast<const bf16x8*>(&Bs[row * BK + slot * 8]);
            }
#pragma unroll
            for (int m = 0; m < 4; ++m)
#pragma unroll
                for (int n = 0; n < 4; ++n)
                    acc[m][n] = __builtin_amdgcn_mfma_f32_16x16x32_bf16(
                        bfr[n], af[m], acc[m][n], 0, 0, 0);
        }
    }
    // D map (swapped): row = lane&15 (A axis), col = n*16 + lg*4 + i (B axis)
#pragma unroll
    for (int m = 0; m < 4; ++m) {
        int row = bm * BM + wr * 64 + m * 16 + lr;
#pragma unroll
        for (int n = 0; n < 4; ++n) {
            int colb = bn * BN + wc * 64 + n * 16 + lg * 4;
            float4 bv = *reinterpret_cast<const float4*>(&bias[colb]);
            u16x4 pk;
            pk.x = f2bf(acc[m][n][0] + bv.x);
            pk.y = f2bf(acc[m][n][1] + bv.y);
            pk.z = f2bf(acc[m][n][2] + bv.z);
            pk.w = f2bf(acc[m][n][3] + bv.w);
            *reinterpret_cast<u16x4*>(&Z[(size_t)row * N3 + colb]) = pk;
        }
    }
}

// ---------------------------------------------------------------- V transpose
__global__ __launch_bounds__(256) void transpose_v(
    const unsigned short* __restrict__ Z, unsigned short* __restrict__ Vt) {
    __shared__ unsigned short tile[64][72];
    int bid = blockIdx.x;
    int nh = bid >> 5;
    int cb = bid & 31;
    int n = nh >> 4, h = nh & 15;
    int t = threadIdx.x;
#pragma unroll
    for (int p = 0; p < 4; ++p) {
        int idx = p * 256 + t;
        int r = idx >> 4;
        int cg = idx & 15;
        u16x4 v = *reinterpret_cast<const u16x4*>(
            &Z[(size_t)(n * S_LEN + cb * 64 + r) * N3 + 2 * D_MODEL + h * HD + cg * 4]);
        *reinterpret_cast<u16x4*>(&tile[r][cg * 4]) = v;
    }
    __syncthreads();
#pragma unroll
    for (int p = 0; p < 4; ++p) {
        int idx = p * 256 + t;
        int d = idx >> 4;
        int cg = idx & 15;
        u16x4 o;
        o.x = tile[cg * 4 + 0][d];
        o.y = tile[cg * 4 + 1][d];
        o.z = tile[cg * 4 + 2][d];
        o.w = tile[cg * 4 + 3][d];
        *reinterpret_cast<u16x4*>(
            &Vt[((size_t)nh * 64 + d) * S_LEN + cb * 64 + cg * 4]) = o;
    }
}

// ---------------------------------------------------------------- flash attention
// Max-free shift-invariant softmax (exp2 cannot overflow: |s| <= ~104),
// row-sum on the MFMA pipe, swapped QK & PV keep q on the lane axis.
// Dispatch order: balanced quads (31-j, 16+j, 15-j, j) so co-resident blocks
// mix heavy/light work -> no LPT drain tail (was: qb-descending).
__global__ __launch_bounds__(256, 4) void attn(
    const unsigned short* __restrict__ Z, const unsigned short* __restrict__ Vt,
    float* __restrict__ Out) {
    const int ilin = blockIdx.y * 32 + blockIdx.x;
    const int head32 = (ilin & 7) * 4 + ((ilin >> 3) & 3);   // 4 heads per XCD
    const int p = ilin >> 5;                                  // 0..31
    const int pj = p >> 2, pk = p & 3;
    const int qb = (pk == 0) ? 31 - pj
                 : (pk == 1) ? 16 + pj
                 : (pk == 2) ? 15 - pj
                 : pj;                                        // balanced quads
    const int n = head32 >> 4, h = head32 & 15;

    __shared__ unsigned short Kt[2][64 * 64];      // 16 KB
    __shared__ unsigned short Vs[2][64 * 64];      // 16 KB
    __shared__ unsigned short p_lds[4][16 * 64];   // 8 KB, XOR-swizzled slots

    const int t = threadIdx.x;
    const int lane = t & 63, w = t >> 6;
    const int lr = lane & 15, lg = lane >> 4;
    const int r7 = lr & 7;
    const int srow = lane >> 3, sslot = lane & 7;

    const float SCL = 0.03125f * 1.44269504f;   // 1/sqrt(1024) * log2(e)

    // Q fragment (B-operand of swapped QK: lane&15 = q), pre-scaled by SCL
    const size_t zrowQ = (size_t)(n * S_LEN + qb * 64 + w * 16 + lr) * N3 + D_MODEL + h * HD;
    bf16x8 qf[2];
#pragma unroll
    for (int f = 0; f < 2; ++f) {
        bf16x8 raw = *reinterpret_cast<const bf16x8*>(&Z[zrowQ + f * 32 + lg * 8]);
        bf16x8 sc;
#pragma unroll
        for (int j = 0; j < 8; ++j)
            sc[j] = (short)f2bf(bf2f((unsigned short)raw[j]) * SCL);
        qf[f] = sc;
    }
    bf16x8 ones;
#pragma unroll
    for (int j = 0; j < 8; ++j) ones[j] = (short)0x3F80;   // 1.0 bf16

    auto STAGE = [&](int buf, int kb) {
#pragma unroll
        for (int p2 = 0; p2 < 2; ++p2) {
            int rb = w * 16 + p2 * 8;
            int row = rb + srow;
            int seg = sslot ^ (row & 7);
            GLOAD_LDS(&Z[(size_t)(n * S_LEN + kb * 64 + row) * N3 + h * HD + seg * 8],
                      &Kt[buf][rb * 64]);
            GLOAD_LDS(&Vt[((size_t)head32 * 64 + row) * S_LEN + kb * 64 + seg * 8],
                      &Vs[buf][rb * 64]);
        }
    };

    f32x4 o[4] = {};
    f32x4 osum = {};                       // all 4 components = running sum(P)
    unsigned short* pw = &p_lds[w][0];

    STAGE(0, 0);
    int cur = 0;
    for (int kb = 0; kb <= qb; ++kb) {
        __syncthreads();
        if (kb < qb) STAGE(cur ^ 1, kb + 1);
        const unsigned short* Kc = &Kt[cur][0];
        const unsigned short* Vc = &Vs[cur][0];

        // ---- S^T = K Q^T : lane holds s[cf][i] = S[key=cf*16+lg*4+i][q=lr]
        f32x4 s[4];
        __builtin_amdgcn_s_setprio(1);
#pragma unroll
        for (int cf = 0; cf < 4; ++cf) {
            int row = cf * 16 + lr;           // row&7 == lr&7
            bf16x8 kf0 = *reinterpret_cast<const bf16x8*>(
                &Kc[row * 64 + (lg ^ r7) * 8]);
            bf16x8 kf1 = *reinterpret_cast<const bf16x8*>(
                &Kc[row * 64 + ((lg + 4) ^ r7) * 8]);
            f32x4 a = {};
            a = __builtin_amdgcn_mfma_f32_16x16x32_bf16(kf0, qf[0], a, 0, 0, 0);
            a = __builtin_amdgcn_mfma_f32_16x16x32_bf16(kf1, qf[1], a, 0, 0, 0);
            s[cf] = a;
        }
        __builtin_amdgcn_s_setprio(0);

        // ---- causal mask (diag tile only)
        if (kb == qb) {
            const int qloc = w * 16 + lr;
#pragma unroll
            for (int cf = 0; cf < 4; ++cf) {
                int kbase = cf * 16 + lg * 4;
#pragma unroll
                for (int i = 0; i < 4; ++i)
                    if (kbase + i > qloc) s[cf][i] = -1e30f;
            }
        }

        // ---- P = exp2(s) (no max-sub: shift cancels in the final divide);
        //      v_perm truncate-pack -> swizzled per-wave LDS
#pragma unroll
        for (int cf = 0; cf < 4; ++cf) {
#pragma unroll
            for (int i = 0; i < 4; ++i) s[cf][i] = exp2f(s[cf][i]);
            unsigned int lo01 = __builtin_amdgcn_perm(
                __float_as_uint(s[cf][1]), __float_as_uint(s[cf][0]), 0x07060302u);
            unsigned int lo23 = __builtin_amdgcn_perm(
                __float_as_uint(s[cf][3]), __float_as_uint(s[cf][2]), 0x07060302u);
            unsigned long long pk2 = (unsigned long long)lo01 |
                                     ((unsigned long long)lo23 << 32);
            int slot16 = (2 * cf + (lg >> 1)) ^ r7;
            *reinterpret_cast<unsigned long long*>(
                &pw[lr * 64 + slot16 * 8 + (lg & 1) * 4]) = pk2;
        }

        // ---- O += V * P ; row-sum on the MFMA pipe via ones-operand
        __builtin_amdgcn_s_setprio(1);
#pragma unroll
        for (int ks = 0; ks < 2; ++ks) {
            bf16x8 pf = *reinterpret_cast<const bf16x8*>(
                &pw[lr * 64 + ((ks * 4 + lg) ^ r7) * 8]);
            osum = __builtin_amdgcn_mfma_f32_16x16x32_bf16(ones, pf, osum, 0, 0, 0);
#pragma unroll
            for (int cfd = 0; cfd < 4; ++cfd) {
                int vrow = cfd * 16 + lr;     // vrow&7 == lr&7
                bf16x8 vf = *reinterpret_cast<const bf16x8*>(
                    &Vc[vrow * 64 + ((ks * 4 + lg) ^ r7) * 8]);
                o[cfd] = __builtin_amdgcn_mfma_f32_16x16x32_bf16(
                    vf, pf, o[cfd], 0, 0, 0);
            }
        }
        __builtin_amdgcn_s_setprio(0);
        cur ^= 1;
    }
    // ---- epilogue: in-lane divide, float4 stores
    {
        float inv = 1.0f / osum[0];
        int q = qb * 64 + w * 16 + lr;
#pragma unroll
        for (int cfd = 0; cfd < 4; ++cfd) {
            int dbase = h * HD + cfd * 16 + lg * 4;
            float4 ov;
            ov.x = o[cfd][0] * inv;
            ov.y = o[cfd][1] * inv;
            ov.z = o[cfd][2] * inv;
            ov.w = o[cfd][3] * inv;
            *reinterpret_cast<float4*>(
                &Out[(size_t)(n * S_LEN + q) * D_MODEL + dbase]) = ov;
        }
    }
}

// ----------------------------------------------------------------
extern "C" void kernel_launch(void* const* d_in, const int* in_sizes, int n_in,
                              void* d_out, int out_size, void* d_ws, size_t ws_size,
                              hipStream_t stream) {
    const float* x = (const float*)d_in[0];
    const float* W = (const float*)d_in[1];
    const float* b = (const float*)d_in[2];
    float* out = (float*)d_out;

    char* ws = (char*)d_ws;
    unsigned short* xb = (unsigned short*)ws;                                  // 8 MB
    unsigned short* Wb = (unsigned short*)(ws + (size_t)8 * 1024 * 1024);      // 6 MB
    unsigned short* Z  = (unsigned short*)(ws + (size_t)14 * 1024 * 1024);     // 24 MB
    unsigned short* Vt = (unsigned short*)(ws + (size_t)38 * 1024 * 1024);     // 8 MB

    cast_both<<<7168, 256, 0, stream>>>(x, W, xb, Wb);
    qkv_gemm<<<dim3(N3 / BN, M_TOT / BM), 256, 0, stream>>>(xb, Wb, b, Z);
    transpose_v<<<1024, 256, 0, stream>>>(Z, Vt);
    attn<<<dim3(32, 32), 256, 0, stream>>>(Z, Vt, out);
}

// Round 10
// 159.278 us; speedup vs baseline: 1.0544x; 1.0544x over previous
//
#include <hip/hip_runtime.h>
#include <hip/hip_bf16.h>

#define D_MODEL 1024
#define NH 16
#define HD 64
#define S_LEN 2048
#define NB 2
#define M_TOT 4096
#define N3 3072

typedef __attribute__((ext_vector_type(8))) short bf16x8;
typedef __attribute__((ext_vector_type(4))) float f32x4;
typedef __attribute__((ext_vector_type(4))) unsigned short u16x4;

__device__ __forceinline__ unsigned short f2bf(float f) {
    unsigned int u = __float_as_uint(f);
    u += 0x7fffu + ((u >> 16) & 1u);
    return (unsigned short)(u >> 16);
}
__device__ __forceinline__ float bf2f(unsigned short s) {
    return __uint_as_float((unsigned int)s << 16);
}

#define GLOAD_LDS(gp, lp)                                                      \
    __builtin_amdgcn_global_load_lds(                                          \
        (const __attribute__((address_space(1))) void*)(gp),                   \
        (__attribute__((address_space(3))) void*)(lp), 16, 0, 0)

// ---------------------------------------------------------------- fused casts
__global__ __launch_bounds__(256) void cast_both(
    const float* __restrict__ x, const float* __restrict__ W,
    unsigned short* __restrict__ xb, unsigned short* __restrict__ Wb) {
    const int nx = M_TOT * D_MODEL / 4;
    const int nw = N3 * D_MODEL / 4;
    int i = blockIdx.x * 256 + threadIdx.x;
    const float* src;
    unsigned short* dst;
    int j;
    if (i < nx) { src = x; dst = xb; j = i; }
    else { j = i - nx; if (j >= nw) return; src = W; dst = Wb; }
    float4 v = reinterpret_cast<const float4*>(src)[j];
    u16x4 o;
    o.x = f2bf(v.x); o.y = f2bf(v.y); o.z = f2bf(v.z); o.w = f2bf(v.w);
    reinterpret_cast<u16x4*>(dst)[j] = o;
}

// ---------------------------------------------------------------- QKV GEMM
// m97 structure; swapped mfma(B,A); bijective XCD swizzle (768 % 8 == 0).
#define BM 128
#define BN 128
#define BK 64

__global__ __launch_bounds__(256) void qkv_gemm(
    const unsigned short* __restrict__ A, const unsigned short* __restrict__ B,
    const float* __restrict__ bias, unsigned short* __restrict__ Z) {
    __shared__ unsigned short As[BM * BK];
    __shared__ unsigned short Bs[BN * BK];

    const int t = threadIdx.x;
    const int lane = t & 63;
    const int wid = t >> 6;
    const int wr = wid >> 1, wc = wid & 1;
    // XCD-aware swizzle: 768 workgroups, 8 XCDs, 96 per XCD (bijective)
    const int lin = blockIdx.y * 24 + blockIdx.x;
    const int swz = (lin & 7) * 96 + (lin >> 3);
    const int bm = swz / 24, bn = swz % 24;
    const int lr = lane & 15;
    const int lg = lane >> 4;
    const int srow = lane >> 3;
    const int sslot = lane & 7;

    f32x4 acc[4][4] = {};

    for (int k0 = 0; k0 < 1024; k0 += BK) {
        __syncthreads();
#pragma unroll
        for (int p = 0; p < 4; ++p) {
            int rb = wid * 32 + p * 8;
            int row = rb + srow;
            int seg = sslot ^ (row & 7);
            GLOAD_LDS(&A[(size_t)(bm * BM + row) * 1024 + k0 + seg * 8],
                      &As[rb * BK]);
            GLOAD_LDS(&B[(size_t)(bn * BN + row) * 1024 + k0 + seg * 8],
                      &Bs[rb * BK]);
        }
        __syncthreads();
#pragma unroll
        for (int ks = 0; ks < 2; ++ks) {
            bf16x8 af[4], bfr[4];
#pragma unroll
            for (int m = 0; m < 4; ++m) {
                int row = wr * 64 + m * 16 + lr;
                int slot = (ks * 4 + lg) ^ (row & 7);
                af[m] = *reinterpret_cast<const bf16x8*>(&As[row * BK + slot * 8]);
            }
#pragma unroll
            for (int n = 0; n < 4; ++n) {
                int row = wc * 64 + n * 16 + lr;
                int slot = (ks * 4 + lg) ^ (row & 7);
                bfr[n] = *reinterpret_cast<const bf16x8*>(&Bs[row * BK + slot * 8]);
            }
#pragma unroll
            for (int m = 0; m < 4; ++m)
#pragma unroll
                for (int n = 0; n < 4; ++n)
                    acc[m][n] = __builtin_amdgcn_mfma_f32_16x16x32_bf16(
                        bfr[n], af[m], acc[m][n], 0, 0, 0);
        }
    }
    // D map (swapped): row = lane&15 (A axis), col = n*16 + lg*4 + i (B axis)
#pragma unroll
    for (int m = 0; m < 4; ++m) {
        int row = bm * BM + wr * 64 + m * 16 + lr;
#pragma unroll
        for (int n = 0; n < 4; ++n) {
            int colb = bn * BN + wc * 64 + n * 16 + lg * 4;
            float4 bv = *reinterpret_cast<const float4*>(&bias[colb]);
            u16x4 pk;
            pk.x = f2bf(acc[m][n][0] + bv.x);
            pk.y = f2bf(acc[m][n][1] + bv.y);
            pk.z = f2bf(acc[m][n][2] + bv.z);
            pk.w = f2bf(acc[m][n][3] + bv.w);
            *reinterpret_cast<u16x4*>(&Z[(size_t)row * N3 + colb]) = pk;
        }
    }
}

// ---------------------------------------------------------------- V transpose
__global__ __launch_bounds__(256) void transpose_v(
    const unsigned short* __restrict__ Z, unsigned short* __restrict__ Vt) {
    __shared__ unsigned short tile[64][72];
    int bid = blockIdx.x;
    int nh = bid >> 5;
    int cb = bid & 31;
    int n = nh >> 4, h = nh & 15;
    int t = threadIdx.x;
#pragma unroll
    for (int p = 0; p < 4; ++p) {
        int idx = p * 256 + t;
        int r = idx >> 4;
        int cg = idx & 15;
        u16x4 v = *reinterpret_cast<const u16x4*>(
            &Z[(size_t)(n * S_LEN + cb * 64 + r) * N3 + 2 * D_MODEL + h * HD + cg * 4]);
        *reinterpret_cast<u16x4*>(&tile[r][cg * 4]) = v;
    }
    __syncthreads();
#pragma unroll
    for (int p = 0; p < 4; ++p) {
        int idx = p * 256 + t;
        int d = idx >> 4;
        int cg = idx & 15;
        u16x4 o;
        o.x = tile[cg * 4 + 0][d];
        o.y = tile[cg * 4 + 1][d];
        o.z = tile[cg * 4 + 2][d];
        o.w = tile[cg * 4 + 3][d];
        *reinterpret_cast<u16x4*>(
            &Vt[((size_t)nh * 64 + d) * S_LEN + cb * 64 + cg * 4]) = o;
    }
}

// ---------------------------------------------------------------- flash attention
// Max-free shift-invariant softmax, row-sum on the MFMA pipe, swapped QK & PV.
// Dispatch->CU model (fits r8/r9 data): block i -> XCD i%8, CU (i/8)%32, so
// same-CU blocks are ilin = c, c+256, c+512, c+768 (stride 8 in p = ilin>>5).
// qb map balances THOSE groups: each CU's 4 blocks get qb quads with constant
// sum 62 and tight spread ({12,15,16,19}-style nested pairs).
__global__ __launch_bounds__(256, 4) void attn(
    const unsigned short* __restrict__ Z, const unsigned short* __restrict__ Vt,
    float* __restrict__ Out) {
    const int ilin = blockIdx.y * 32 + blockIdx.x;
    const int head32 = (ilin & 7) * 4 + ((ilin >> 3) & 3);   // 4 heads per XCD
    const int p = ilin >> 5;                                  // 0..31
    const int p0 = p & 7;      // same-CU group id
    const int pj = p >> 3;     // member within the group (stride-256 quads)
    // nested-pair quad: {31-(b^3), 31-b, b, b^3}, b = 16 + ((p0&6)<<1) + (p0&1)
    const int bqs = 16 + ((p0 & 6) << 1) + (p0 & 1);
    const int tq = bqs ^ (((pj ^ (pj >> 1)) & 1) ? 0 : 3);
    const int qb = (pj >= 2) ? tq : 31 - tq;
    const int n = head32 >> 4, h = head32 & 15;

    __shared__ unsigned short Kt[2][64 * 64];      // 16 KB
    __shared__ unsigned short Vs[2][64 * 64];      // 16 KB
    __shared__ unsigned short p_lds[4][16 * 64];   // 8 KB, XOR-swizzled slots

    const int t = threadIdx.x;
    const int lane = t & 63, w = t >> 6;
    const int lr = lane & 15, lg = lane >> 4;
    const int r7 = lr & 7;
    const int srow = lane >> 3, sslot = lane & 7;

    const float SCL = 0.03125f * 1.44269504f;   // 1/sqrt(1024) * log2(e)

    // Q fragment (B-operand of swapped QK: lane&15 = q), pre-scaled by SCL
    const size_t zrowQ = (size_t)(n * S_LEN + qb * 64 + w * 16 + lr) * N3 + D_MODEL + h * HD;
    bf16x8 qf[2];
#pragma unroll
    for (int f = 0; f < 2; ++f) {
        bf16x8 raw = *reinterpret_cast<const bf16x8*>(&Z[zrowQ + f * 32 + lg * 8]);
        bf16x8 sc;
#pragma unroll
        for (int j = 0; j < 8; ++j)
            sc[j] = (short)f2bf(bf2f((unsigned short)raw[j]) * SCL);
        qf[f] = sc;
    }
    bf16x8 ones;
#pragma unroll
    for (int j = 0; j < 8; ++j) ones[j] = (short)0x3F80;   // 1.0 bf16

    auto STAGE = [&](int buf, int kb) {
#pragma unroll
        for (int p2 = 0; p2 < 2; ++p2) {
            int rb = w * 16 + p2 * 8;
            int row = rb + srow;
            int seg = sslot ^ (row & 7);
            GLOAD_LDS(&Z[(size_t)(n * S_LEN + kb * 64 + row) * N3 + h * HD + seg * 8],
                      &Kt[buf][rb * 64]);
            GLOAD_LDS(&Vt[((size_t)head32 * 64 + row) * S_LEN + kb * 64 + seg * 8],
                      &Vs[buf][rb * 64]);
        }
    };

    f32x4 o[4] = {};
    f32x4 osum = {};                       // all 4 components = running sum(P)
    unsigned short* pw = &p_lds[w][0];

    STAGE(0, 0);
    int cur = 0;
    for (int kb = 0; kb <= qb; ++kb) {
        __syncthreads();
        if (kb < qb) STAGE(cur ^ 1, kb + 1);
        const unsigned short* Kc = &Kt[cur][0];
        const unsigned short* Vc = &Vs[cur][0];

        // ---- S^T = K Q^T : lane holds s[cf][i] = S[key=cf*16+lg*4+i][q=lr]
        f32x4 s[4];
        __builtin_amdgcn_s_setprio(1);
#pragma unroll
        for (int cf = 0; cf < 4; ++cf) {
            int row = cf * 16 + lr;           // row&7 == lr&7
            bf16x8 kf0 = *reinterpret_cast<const bf16x8*>(
                &Kc[row * 64 + (lg ^ r7) * 8]);
            bf16x8 kf1 = *reinterpret_cast<const bf16x8*>(
                &Kc[row * 64 + ((lg + 4) ^ r7) * 8]);
            f32x4 a = {};
            a = __builtin_amdgcn_mfma_f32_16x16x32_bf16(kf0, qf[0], a, 0, 0, 0);
            a = __builtin_amdgcn_mfma_f32_16x16x32_bf16(kf1, qf[1], a, 0, 0, 0);
            s[cf] = a;
        }
        __builtin_amdgcn_s_setprio(0);

        // ---- causal mask (diag tile only)
        if (kb == qb) {
            const int qloc = w * 16 + lr;
#pragma unroll
            for (int cf = 0; cf < 4; ++cf) {
                int kbase = cf * 16 + lg * 4;
#pragma unroll
                for (int i = 0; i < 4; ++i)
                    if (kbase + i > qloc) s[cf][i] = -1e30f;
            }
        }

        // ---- P = exp2(s) (no max-sub: shift cancels in the final divide);
        //      v_perm truncate-pack -> swizzled per-wave LDS
#pragma unroll
        for (int cf = 0; cf < 4; ++cf) {
#pragma unroll
            for (int i = 0; i < 4; ++i) s[cf][i] = exp2f(s[cf][i]);
            unsigned int lo01 = __builtin_amdgcn_perm(
                __float_as_uint(s[cf][1]), __float_as_uint(s[cf][0]), 0x07060302u);
            unsigned int lo23 = __builtin_amdgcn_perm(
                __float_as_uint(s[cf][3]), __float_as_uint(s[cf][2]), 0x07060302u);
            unsigned long long pk2 = (unsigned long long)lo01 |
                                     ((unsigned long long)lo23 << 32);
            int slot16 = (2 * cf + (lg >> 1)) ^ r7;
            *reinterpret_cast<unsigned long long*>(
                &pw[lr * 64 + slot16 * 8 + (lg & 1) * 4]) = pk2;
        }

        // ---- O += V * P ; row-sum on the MFMA pipe via ones-operand
        __builtin_amdgcn_s_setprio(1);
#pragma unroll
        for (int ks = 0; ks < 2; ++ks) {
            bf16x8 pf = *reinterpret_cast<const bf16x8*>(
                &pw[lr * 64 + ((ks * 4 + lg) ^ r7) * 8]);
            osum = __builtin_amdgcn_mfma_f32_16x16x32_bf16(ones, pf, osum, 0, 0, 0);
#pragma unroll
            for (int cfd = 0; cfd < 4; ++cfd) {
                int vrow = cfd * 16 + lr;     // vrow&7 == lr&7
                bf16x8 vf = *reinterpret_cast<const bf16x8*>(
                    &Vc[vrow * 64 + ((ks * 4 + lg) ^ r7) * 8]);
                o[cfd] = __builtin_amdgcn_mfma_f32_16x16x32_bf16(
                    vf, pf, o[cfd], 0, 0, 0);
            }
        }
        __builtin_amdgcn_s_setprio(0);
        cur ^= 1;
    }
    // ---- epilogue: in-lane divide, float4 stores
    {
        float inv = 1.0f / osum[0];
        int q = qb * 64 + w * 16 + lr;
#pragma unroll
        for (int cfd = 0; cfd < 4; ++cfd) {
            int dbase = h * HD + cfd * 16 + lg * 4;
            float4 ov;
            ov.x = o[cfd][0] * inv;
            ov.y = o[cfd][1] * inv;
            ov.z = o[cfd][2] * inv;
            ov.w = o[cfd][3] * inv;
            *reinterpret_cast<float4*>(
                &Out[(size_t)(n * S_LEN + q) * D_MODEL + dbase]) = ov;
        }
    }
}

// ----------------------------------------------------------------
extern "C" void kernel_launch(void* const* d_in, const int* in_sizes, int n_in,
                              void* d_out, int out_size, void* d_ws, size_t ws_size,
                              hipStream_t stream) {
    const float* x = (const float*)d_in[0];
    const float* W = (const float*)d_in[1];
    const float* b = (const float*)d_in[2];
    float* out = (float*)d_out;

    char* ws = (char*)d_ws;
    unsigned short* xb = (unsigned short*)ws;                                  // 8 MB
    unsigned short* Wb = (unsigned short*)(ws + (size_t)8 * 1024 * 1024);      // 6 MB
    unsigned short* Z  = (unsigned short*)(ws + (size_t)14 * 1024 * 1024);     // 24 MB
    unsigned short* Vt = (unsigned short*)(ws + (size_t)38 * 1024 * 1024);     // 8 MB

    cast_both<<<7168, 256, 0, stream>>>(x, W, xb, Wb);
    qkv_gemm<<<dim3(N3 / BN, M_TOT / BM), 256, 0, stream>>>(xb, Wb, b, Z);
    transpose_v<<<1024, 256, 0, stream>>>(Z, Vt);
    attn<<<dim3(32, 32), 256, 0, stream>>>(Z, Vt, out);
}